// Round 1
// baseline (168.302 us; speedup 1.0000x reference)
//
#include <hip/hip_runtime.h>
#include <hip/hip_bf16.h>
#include <stdint.h>

// Problem constants: B=8, T=2048, C=1024, H=64. Single-head causal attention.
#define Bn 8
#define Tn 2048
#define Cn 1024
#define Hn 64

typedef __attribute__((ext_vector_type(8))) short bf16x8;  // 8 bf16 = 4 VGPRs (MFMA A/B frag)
typedef __attribute__((ext_vector_type(4))) float f32x4;   // MFMA C/D frag

__device__ __forceinline__ unsigned short f2bf(float f) {
  union { float f; unsigned int u; } v; v.f = f;
  unsigned int u = v.u;
  u = u + 0x7fffu + ((u >> 16) & 1u);   // round-nearest-even
  return (unsigned short)(u >> 16);
}

// ---------------------------------------------------------------------------
// k_prep: Wt[m][h][c] = W_m[c][h] as bf16.  grid=192 (m*64+h), block=256.
// ---------------------------------------------------------------------------
__global__ __launch_bounds__(256) void k_prep(const float* __restrict__ Wq,
                                              const float* __restrict__ Wk,
                                              const float* __restrict__ Wv,
                                              unsigned short* __restrict__ Wt) {
  const int m = blockIdx.x >> 6;
  const int h = blockIdx.x & 63;
  const float* W = (m == 0) ? Wq : (m == 1) ? Wk : Wv;
  const int tid = threadIdx.x;
  unsigned short* dst = Wt + ((size_t)(m * 64 + h)) * 1024;
#pragma unroll
  for (int j = 0; j < 4; ++j) {
    int c = j * 256 + tid;
    dst[c] = f2bf(W[(size_t)c * 64 + h]);
  }
}

// ---------------------------------------------------------------------------
// k_qkv: C[16384 x 192] = x[16384 x 1024] * W[1024 x 192] (Q|K|V), bf16 MFMA.
// Tile 64 rows x 192 cols per block, BK=64, grid=256, block=256 (4 waves 2x2).
// Outputs: Q,K bf16 [B*T][64] row-major; V transposed -> Vt bf16 [B][64][T].
// ---------------------------------------------------------------------------
__global__ __launch_bounds__(256) void k_qkv(const float* __restrict__ x,
                                             const unsigned short* __restrict__ Wt,
                                             unsigned short* __restrict__ Q,
                                             unsigned short* __restrict__ K,
                                             unsigned short* __restrict__ Vt) {
  // xs[64][72] + wsh[192][72] (pad +8 -> 144B stride: 2-way bank alias = free).
  // os[64][200] aliases them for the epilogue (after the last barrier).
  __shared__ __align__(16) char smem[51200];
  unsigned short (*xs)[72] = (unsigned short (*)[72])smem;
  unsigned short (*wsh)[72] = (unsigned short (*)[72])(smem + 64 * 72 * 2);
  unsigned short (*os)[200] = (unsigned short (*)[200])smem;

  const int tid = threadIdx.x;
  const int lane = tid & 63;
  const int wid = tid >> 6;
  const int wm = wid >> 1, wn = wid & 1;
  const int l15 = lane & 15, g = lane >> 4;
  const int r0 = blockIdx.x * 64;

  f32x4 acc[2][6];
#pragma unroll
  for (int i = 0; i < 2; ++i)
#pragma unroll
    for (int j = 0; j < 6; ++j)
#pragma unroll
      for (int r = 0; r < 4; ++r) acc[i][j][r] = 0.f;

  const int srow = tid >> 2;          // 0..63
  const int skq = (tid & 3) * 16;     // 0,16,32,48

  for (int kt = 0; kt < 16; ++kt) {
    const int k0 = kt * 64;
    // stage x (fp32 -> bf16)
    const float* xp = x + (size_t)(r0 + srow) * 1024 + k0 + skq;
#pragma unroll
    for (int j = 0; j < 4; ++j) {
      float4 v = *(const float4*)(xp + 4 * j);
      ushort4 bv;
      bv.x = f2bf(v.x); bv.y = f2bf(v.y); bv.z = f2bf(v.z); bv.w = f2bf(v.w);
      *(ushort4*)&xs[srow][skq + 4 * j] = bv;
    }
    // stage Wt slice (bf16, 16B vector copies)
#pragma unroll
    for (int j = 0; j < 6; ++j) {
      int u = j * 256 + tid;
      int row = u >> 3, ch = u & 7;
      uint4 w = *(const uint4*)(Wt + (size_t)row * 1024 + k0 + ch * 8);
      *(uint4*)&wsh[row][ch * 8] = w;
    }
    __syncthreads();
#pragma unroll
    for (int kf = 0; kf < 2; ++kf) {
      bf16x8 a[2], bfr[6];
#pragma unroll
      for (int mf = 0; mf < 2; ++mf)
        a[mf] = *(const bf16x8*)&xs[wm * 32 + mf * 16 + l15][kf * 32 + g * 8];
#pragma unroll
      for (int nf = 0; nf < 6; ++nf)
        bfr[nf] = *(const bf16x8*)&wsh[wn * 96 + nf * 16 + l15][kf * 32 + g * 8];
#pragma unroll
      for (int mf = 0; mf < 2; ++mf)
#pragma unroll
        for (int nf = 0; nf < 6; ++nf)
          acc[mf][nf] = __builtin_amdgcn_mfma_f32_16x16x32_bf16(a[mf], bfr[nf], acc[mf][nf], 0, 0, 0);
    }
    __syncthreads();
  }

  // epilogue: acc -> os (bf16).  D layout: col = l&15, row = 4*(l>>4)+reg.
#pragma unroll
  for (int mf = 0; mf < 2; ++mf)
#pragma unroll
    for (int nf = 0; nf < 6; ++nf)
#pragma unroll
      for (int r = 0; r < 4; ++r)
        os[wm * 32 + mf * 16 + 4 * g + r][wn * 96 + nf * 16 + l15] = f2bf(acc[mf][nf][r]);
  __syncthreads();

  const int b = r0 >> 11;
  const int t0 = r0 & 2047;
  // Q, K: coalesced 16B row copies
#pragma unroll
  for (int j = 0; j < 2; ++j) {
    int u = j * 256 + tid;
    int row = u >> 3, ch = u & 7;
    *(uint4*)(Q + (size_t)(r0 + row) * 64 + ch * 8) = *(const uint4*)&os[row][ch * 8];
    *(uint4*)(K + (size_t)(r0 + row) * 64 + ch * 8) = *(const uint4*)&os[row][64 + ch * 8];
  }
  // V: transpose via LDS -> Vt[b][h][t]
#pragma unroll
  for (int j = 0; j < 2; ++j) {
    int u = j * 256 + tid;
    int h = u >> 3, tc = u & 7;
    unsigned short tmp[8];
#pragma unroll
    for (int r = 0; r < 8; ++r) tmp[r] = os[tc * 8 + r][128 + h];
    *(uint4*)(Vt + ((size_t)b * 64 + h) * 2048 + t0 + tc * 8) = *(const uint4*)tmp;
  }
}

// ---------------------------------------------------------------------------
// k_attn: flash attention, causal. grid=(32,8), block=256 (4 waves x 16 qrows).
// K/V read straight from L2 (256KB/batch, cache-resident) — no staging.
// Softmax scale = C^-0.5 = 1/32 (reference scales by num_channels, not H).
// ---------------------------------------------------------------------------
__global__ __launch_bounds__(256) void k_attn(const unsigned short* __restrict__ Q,
                                              const unsigned short* __restrict__ K,
                                              const unsigned short* __restrict__ Vt,
                                              float* __restrict__ out) {
  __shared__ unsigned short plds[4][16][88];  // per-wave P transpose buffer (112B stride)
  const int tid = threadIdx.x;
  const int lane = tid & 63;
  const int wid = tid >> 6;
  const int l15 = lane & 15, g = lane >> 4;
  const int b = blockIdx.y;
  const int q0 = blockIdx.x * 64 + wid * 16;

  const unsigned short* Qb = Q + (size_t)b * Tn * Hn;
  const unsigned short* Kb = K + (size_t)b * Tn * Hn;
  const unsigned short* Vb = Vt + (size_t)b * Hn * Tn;

  // Q A-fragments (row = l&15, k = 8*(l>>4)+j), h split 0..31 / 32..63
  bf16x8 aq0 = *(const bf16x8*)(Qb + (size_t)(q0 + l15) * 64 + g * 8);
  bf16x8 aq1 = *(const bf16x8*)(Qb + (size_t)(q0 + l15) * 64 + 32 + g * 8);

  f32x4 o[4];
  float m[4], lsum[4];
#pragma unroll
  for (int r = 0; r < 4; ++r) { m[r] = -1e30f; lsum[r] = 0.f; }
#pragma unroll
  for (int hf = 0; hf < 4; ++hf)
#pragma unroll
    for (int r = 0; r < 4; ++r) o[hf][r] = 0.f;

  unsigned short (*pw)[88] = plds[wid];
  const float sc = 0.03125f * 1.44269504088896f;  // C^-0.5 * log2(e)

  const int nkt = (q0 + 79) >> 6;  // 64-key tiles covering keys <= q0+15
  for (int kt = 0; kt < nkt; ++kt) {
    const int k0 = kt * 64;
    // S = Q K^T  (D layout: col=key=l&15, row=q=4*(l>>4)+reg)
    f32x4 s[4];
#pragma unroll
    for (int kc = 0; kc < 4; ++kc) {
#pragma unroll
      for (int r = 0; r < 4; ++r) s[kc][r] = 0.f;
      const unsigned short* kp = Kb + (size_t)(k0 + kc * 16 + l15) * 64 + g * 8;
      bf16x8 b0 = *(const bf16x8*)kp;
      bf16x8 b1 = *(const bf16x8*)(kp + 32);
      s[kc] = __builtin_amdgcn_mfma_f32_16x16x32_bf16(aq0, b0, s[kc], 0, 0, 0);
      s[kc] = __builtin_amdgcn_mfma_f32_16x16x32_bf16(aq1, b1, s[kc], 0, 0, 0);
    }
    // scale (+ causal mask only on boundary tiles; wave-uniform branch)
    float sv[4][4];
    if (k0 + 63 > q0) {
#pragma unroll
      for (int kc = 0; kc < 4; ++kc) {
        int key = k0 + kc * 16 + l15;
#pragma unroll
        for (int r = 0; r < 4; ++r) {
          int q = q0 + 4 * g + r;
          sv[kc][r] = (key <= q) ? s[kc][r] * sc : -1e30f;
        }
      }
    } else {
#pragma unroll
      for (int kc = 0; kc < 4; ++kc)
#pragma unroll
        for (int r = 0; r < 4; ++r) sv[kc][r] = s[kc][r] * sc;
    }
    // online softmax: row stats across the 16 key-lanes
    float pm[4];
#pragma unroll
    for (int r = 0; r < 4; ++r)
      pm[r] = fmaxf(fmaxf(sv[0][r], sv[1][r]), fmaxf(sv[2][r], sv[3][r]));
#pragma unroll
    for (int d = 1; d < 16; d <<= 1)
#pragma unroll
      for (int r = 0; r < 4; ++r) pm[r] = fmaxf(pm[r], __shfl_xor(pm[r], d));
    float alpha[4];
#pragma unroll
    for (int r = 0; r < 4; ++r) {
      float mn = fmaxf(m[r], pm[r]);
      alpha[r] = exp2f(m[r] - mn);
      m[r] = mn;
    }
    float p[4][4], ts[4];
#pragma unroll
    for (int r = 0; r < 4; ++r) ts[r] = 0.f;
#pragma unroll
    for (int kc = 0; kc < 4; ++kc)
#pragma unroll
      for (int r = 0; r < 4; ++r) { p[kc][r] = exp2f(sv[kc][r] - m[r]); ts[r] += p[kc][r]; }
#pragma unroll
    for (int d = 1; d < 16; d <<= 1)
#pragma unroll
      for (int r = 0; r < 4; ++r) ts[r] += __shfl_xor(ts[r], d);
#pragma unroll
    for (int r = 0; r < 4; ++r) lsum[r] = lsum[r] * alpha[r] + ts[r];
#pragma unroll
    for (int hf = 0; hf < 4; ++hf)
#pragma unroll
      for (int r = 0; r < 4; ++r) o[hf][r] *= alpha[r];
    // P: D-layout -> A-layout via per-wave LDS (no block barrier needed)
#pragma unroll
    for (int kc = 0; kc < 4; ++kc)
#pragma unroll
      for (int r = 0; r < 4; ++r)
        pw[4 * g + r][kc * 16 + l15] = f2bf(p[kc][r]);
    asm volatile("s_waitcnt lgkmcnt(0)" ::: "memory");
    bf16x8 pa0 = *(const bf16x8*)&pw[l15][g * 8];
    bf16x8 pa1 = *(const bf16x8*)&pw[l15][32 + g * 8];
    // O += P V  (B operand from Vt: contiguous keys per lane)
#pragma unroll
    for (int hf = 0; hf < 4; ++hf) {
      const unsigned short* vp = Vb + (size_t)(hf * 16 + l15) * 2048 + k0 + g * 8;
      bf16x8 bv0 = *(const bf16x8*)vp;
      bf16x8 bv1 = *(const bf16x8*)(vp + 32);
      o[hf] = __builtin_amdgcn_mfma_f32_16x16x32_bf16(pa0, bv0, o[hf], 0, 0, 0);
      o[hf] = __builtin_amdgcn_mfma_f32_16x16x32_bf16(pa1, bv1, o[hf], 0, 0, 0);
    }
  }
  float invl[4];
#pragma unroll
  for (int r = 0; r < 4; ++r) invl[r] = 1.f / lsum[r];
  float* ob = out + ((size_t)b * Tn + q0) * 64;
#pragma unroll
  for (int hf = 0; hf < 4; ++hf)
#pragma unroll
    for (int r = 0; r < 4; ++r)
      ob[(size_t)(4 * g + r) * 64 + hf * 16 + l15] = o[hf][r] * invl[r];
}

// ---------------------------------------------------------------------------
extern "C" void kernel_launch(void* const* d_in, const int* in_sizes, int n_in,
                              void* d_out, int out_size, void* d_ws, size_t ws_size,
                              hipStream_t stream) {
  const float* x  = (const float*)d_in[0];
  const float* Wq = (const float*)d_in[1];
  const float* Wk = (const float*)d_in[2];
  const float* Wv = (const float*)d_in[3];
  float* out = (float*)d_out;

  // workspace layout (bf16): Wt[3*64*1024] | Q[B*T*64] | K[B*T*64] | Vt[B*64*T]
  unsigned short* Wt = (unsigned short*)d_ws;
  unsigned short* Qs = Wt + 3 * 64 * 1024;
  unsigned short* Ks = Qs + (size_t)Bn * Tn * Hn;
  unsigned short* Vt = Ks + (size_t)Bn * Tn * Hn;

  hipLaunchKernelGGL(k_prep, dim3(192), dim3(256), 0, stream, Wq, Wk, Wv, Wt);
  hipLaunchKernelGGL(k_qkv, dim3(256), dim3(256), 0, stream, x, Wt, Qs, Ks, Vt);
  hipLaunchKernelGGL(k_attn, dim3(32, 8), dim3(256), 0, stream, Qs, Ks, Vt, out);
}

// Round 2
// 100.315 us; speedup vs baseline: 1.6777x; 1.6777x over previous
//
#include <hip/hip_runtime.h>
#include <hip/hip_bf16.h>
#include <stdint.h>

// Problem constants: B=8, T=2048, C=1024, H=64. Single-head causal attention.
#define Bn 8
#define Tn 2048
#define Cn 1024
#define Hn 64

typedef __attribute__((ext_vector_type(8))) short bf16x8;  // 8 bf16 (MFMA K=32 A/B frag)
typedef __attribute__((ext_vector_type(4))) short bf16x4;  // 4 bf16 (MFMA K=16 A/B frag)
typedef __attribute__((ext_vector_type(4))) float f32x4;   // MFMA C/D frag

#if __has_builtin(__builtin_amdgcn_mfma_f32_16x16x16bf16_1k)
#define HAVE_MFMA16 1
#define MFMA16(a, b, c) __builtin_amdgcn_mfma_f32_16x16x16bf16_1k(a, b, c, 0, 0, 0)
#else
#define HAVE_MFMA16 0
#endif

__device__ __forceinline__ unsigned short f2bf(float f) {
  union { float f; unsigned int u; } v; v.f = f;
  unsigned int u = v.u;
  u = u + 0x7fffu + ((u >> 16) & 1u);   // round-nearest-even
  return (unsigned short)(u >> 16);
}

// ---------------------------------------------------------------------------
// k_prep: Wt[m][h][c] = W_m[c][h] as bf16.  grid=192 (m*64+h), block=256.
// ---------------------------------------------------------------------------
__global__ __launch_bounds__(256) void k_prep(const float* __restrict__ Wq,
                                              const float* __restrict__ Wk,
                                              const float* __restrict__ Wv,
                                              unsigned short* __restrict__ Wt) {
  const int m = blockIdx.x >> 6;
  const int h = blockIdx.x & 63;
  const float* W = (m == 0) ? Wq : (m == 1) ? Wk : Wv;
  const int tid = threadIdx.x;
  unsigned short* dst = Wt + ((size_t)(m * 64 + h)) * 1024;
#pragma unroll
  for (int j = 0; j < 4; ++j) {
    int c = j * 256 + tid;
    dst[c] = f2bf(W[(size_t)c * 64 + h]);
  }
}

// ---------------------------------------------------------------------------
// k_qkv: C[16384 x 192] = x * W (Q|K|V), bf16 MFMA. 32-row x 192-col tiles,
// grid=512 (2 blocks/CU co-resident -> 8 waves/CU), block=256 (4 waves 2x2).
// Outputs: Q,K bf16 [B*T][64] row-major; Vt bf16 [B][64][T] (transposed).
// ---------------------------------------------------------------------------
__global__ __launch_bounds__(256) void k_qkv(const float* __restrict__ x,
                                             const unsigned short* __restrict__ Wt,
                                             unsigned short* __restrict__ Q,
                                             unsigned short* __restrict__ K,
                                             unsigned short* __restrict__ Vt) {
  // xs[32][72] | wsh[192][72]; os[32][200] aliases for the epilogue.
  __shared__ __align__(16) char smem[32256];
  unsigned short (*xs)[72] = (unsigned short (*)[72])smem;
  unsigned short (*wsh)[72] = (unsigned short (*)[72])(smem + 32 * 72 * 2);
  unsigned short (*os)[200] = (unsigned short (*)[200])smem;

  const int tid = threadIdx.x;
  const int lane = tid & 63;
  const int wid = tid >> 6;
  const int wm = wid >> 1, wn = wid & 1;
  const int l15 = lane & 15, g = lane >> 4;
  const int r0 = blockIdx.x * 32;

  f32x4 acc[6];
#pragma unroll
  for (int j = 0; j < 6; ++j)
#pragma unroll
    for (int r = 0; r < 4; ++r) acc[j][r] = 0.f;

  const int srow = tid >> 3;          // 0..31
  const int scol = (tid & 7) * 8;     // 0..56

  for (int kt = 0; kt < 16; ++kt) {
    const int k0 = kt * 64;
    // stage x (fp32 -> bf16): 32 rows x 64 k
    const float* xp = x + (size_t)(r0 + srow) * 1024 + k0 + scol;
    {
      float4 v0 = *(const float4*)xp;
      float4 v1 = *(const float4*)(xp + 4);
      ushort4 b0, b1;
      b0.x = f2bf(v0.x); b0.y = f2bf(v0.y); b0.z = f2bf(v0.z); b0.w = f2bf(v0.w);
      b1.x = f2bf(v1.x); b1.y = f2bf(v1.y); b1.z = f2bf(v1.z); b1.w = f2bf(v1.w);
      *(ushort4*)&xs[srow][scol] = b0;
      *(ushort4*)&xs[srow][scol + 4] = b1;
    }
    // stage Wt slice (192 rows x 64 k bf16)
#pragma unroll
    for (int j = 0; j < 6; ++j) {
      int u = j * 256 + tid;
      int row = u >> 3, ch = u & 7;
      uint4 w = *(const uint4*)(Wt + (size_t)row * 1024 + k0 + ch * 8);
      *(uint4*)&wsh[row][ch * 8] = w;
    }
    __syncthreads();
#pragma unroll
    for (int kf = 0; kf < 2; ++kf) {
      bf16x8 a = *(const bf16x8*)&xs[wm * 16 + l15][kf * 32 + g * 8];
      bf16x8 bfr[6];
#pragma unroll
      for (int nf = 0; nf < 6; ++nf)
        bfr[nf] = *(const bf16x8*)&wsh[wn * 96 + nf * 16 + l15][kf * 32 + g * 8];
#pragma unroll
      for (int nf = 0; nf < 6; ++nf)
        acc[nf] = __builtin_amdgcn_mfma_f32_16x16x32_bf16(a, bfr[nf], acc[nf], 0, 0, 0);
    }
    __syncthreads();
  }

  // epilogue: acc -> os (bf16). D layout: col = l&15, row = 4*(l>>4)+reg.
#pragma unroll
  for (int nf = 0; nf < 6; ++nf)
#pragma unroll
    for (int r = 0; r < 4; ++r)
      os[wm * 16 + 4 * g + r][wn * 96 + nf * 16 + l15] = f2bf(acc[nf][r]);
  __syncthreads();

  const int b = r0 >> 11;
  const int t0 = r0 & 2047;
  // Q, K: coalesced 16B row copies (32 rows x 64 cols = 256 x uint4 each)
  {
    int row = tid >> 3, ch = tid & 7;
    *(uint4*)(Q + (size_t)(r0 + row) * 64 + ch * 8) = *(const uint4*)&os[row][ch * 8];
    *(uint4*)(K + (size_t)(r0 + row) * 64 + ch * 8) = *(const uint4*)&os[row][64 + ch * 8];
  }
  // V transpose -> Vt[b][h][t]
  {
    int h = tid >> 2, tc = (tid & 3) * 8;
    unsigned short tmp[8];
#pragma unroll
    for (int r = 0; r < 8; ++r) tmp[r] = os[tc + r][128 + h];
    *(uint4*)(Vt + ((size_t)b * 64 + h) * 2048 + t0 + tc) = *(const uint4*)tmp;
  }
}

// ---------------------------------------------------------------------------
// k_attn: flash attention, causal, swapped QK^T (lane = q column; keys in regs).
// SPLIT: wave-task = (b, 16-row q-tile, 512-key segment); 2560 tasks, grid 640.
//   Single-segment q-tiles (qt<32) write out directly; others write fp32
//   partials (o unnormalized, m, l) merged by k_comb.
// !SPLIT fallback (small ws): task = (b, qt), full key range, grid 256.
// ---------------------------------------------------------------------------
template <bool SPLIT>
__global__ __launch_bounds__(256) void k_attn(const unsigned short* __restrict__ Q,
                                              const unsigned short* __restrict__ K,
                                              const unsigned short* __restrict__ Vt,
                                              float* __restrict__ out,
                                              float* __restrict__ po,
                                              float* __restrict__ pml) {
#if !HAVE_MFMA16
  __shared__ unsigned short plds[4][16][72];
#endif
  const int tid = threadIdx.x;
  const int lane = tid & 63;
  const int wid = tid >> 6;
  const int l15 = lane & 15, g = lane >> 4;

  int b, qt, s, klo, khi;
  const int task = blockIdx.x * 4 + wid;
  if (SPLIT) {
    b = task / 320;
    int id = task - b * 320;
    if (id < 128)      { s = 0; qt = id; }
    else if (id < 224) { s = 1; qt = id - 96; }
    else if (id < 288) { s = 2; qt = id - 160; }
    else               { s = 3; qt = id - 192; }
    klo = 512 * s;
    khi = min(klo + 512, 16 * qt + 16);
  } else {
    b = task >> 7; qt = task & 127; s = 0;
    klo = 0; khi = 16 * qt + 16;
  }
  const int q0 = qt * 16;

  const unsigned short* Qb = Q + (size_t)b * Tn * Hn;
  const unsigned short* Kb = K + (size_t)b * Tn * Hn;
  const unsigned short* Vb = Vt + (size_t)b * Hn * Tn;

  // Q as B-operand: lane l15 = q row, k = 8g+j
  bf16x8 bq0 = *(const bf16x8*)(Qb + (size_t)(q0 + l15) * 64 + g * 8);
  bf16x8 bq1 = *(const bf16x8*)(Qb + (size_t)(q0 + l15) * 64 + 32 + g * 8);

  f32x4 o[4];
#pragma unroll
  for (int hf = 0; hf < 4; ++hf)
#pragma unroll
    for (int r = 0; r < 4; ++r) o[hf][r] = 0.f;
  float m = -1e30f, lsum = 0.f;
  const float sc = 0.03125f * 1.44269504088896f;  // C^-0.5 * log2(e)

  const int nkt = (khi - klo + 63) >> 6;
  for (int kt = 0; kt < nkt; ++kt) {
    const int k0 = klo + kt * 64;
    // S^T tile: mfma(A=K, B=Q) -> lane l15 = q, reg (kc, 4g+r) = key
    f32x4 sacc[4];
#pragma unroll
    for (int kc = 0; kc < 4; ++kc) {
#pragma unroll
      for (int r = 0; r < 4; ++r) sacc[kc][r] = 0.f;
      const unsigned short* kp = Kb + (size_t)(k0 + kc * 16 + l15) * 64 + g * 8;
      bf16x8 ka0 = *(const bf16x8*)kp;
      bf16x8 ka1 = *(const bf16x8*)(kp + 32);
      sacc[kc] = __builtin_amdgcn_mfma_f32_16x16x32_bf16(ka0, bq0, sacc[kc], 0, 0, 0);
      sacc[kc] = __builtin_amdgcn_mfma_f32_16x16x32_bf16(ka1, bq1, sacc[kc], 0, 0, 0);
    }
    // scale + causal mask (key <= q); only boundary tiles mask (wave-uniform)
    float sv[4][4];
    if (k0 + 63 > q0) {
      const int q = q0 + l15;
#pragma unroll
      for (int kc = 0; kc < 4; ++kc)
#pragma unroll
        for (int r = 0; r < 4; ++r) {
          int key = k0 + kc * 16 + 4 * g + r;
          sv[kc][r] = (key <= q) ? sacc[kc][r] * sc : -1e30f;
        }
    } else {
#pragma unroll
      for (int kc = 0; kc < 4; ++kc)
#pragma unroll
        for (int r = 0; r < 4; ++r) sv[kc][r] = sacc[kc][r] * sc;
    }
    // row max: 15 in-register fmax + 2 cross-group shuffles
    float pm = sv[0][0];
#pragma unroll
    for (int kc = 0; kc < 4; ++kc)
#pragma unroll
      for (int r = 0; r < 4; ++r) pm = fmaxf(pm, sv[kc][r]);
    pm = fmaxf(pm, __shfl_xor(pm, 16));
    pm = fmaxf(pm, __shfl_xor(pm, 32));
    const float mn = fmaxf(m, pm);
    const float alpha = exp2f(m - mn);
    m = mn;
    // P = exp2(sv - m), row sum
    float p[4][4], ts = 0.f;
#pragma unroll
    for (int kc = 0; kc < 4; ++kc)
#pragma unroll
      for (int r = 0; r < 4; ++r) { p[kc][r] = exp2f(sv[kc][r] - mn); ts += p[kc][r]; }
    ts += __shfl_xor(ts, 16);
    ts += __shfl_xor(ts, 32);
    lsum = lsum * alpha + ts;
    // redistribute alpha from softmax lanes (q=l15) to O lanes (q=4g+r)
    float an[4];
#pragma unroll
    for (int r = 0; r < 4; ++r) an[r] = __shfl(alpha, 4 * g + r);
#pragma unroll
    for (int hf = 0; hf < 4; ++hf)
#pragma unroll
      for (int r = 0; r < 4; ++r) o[hf][r] *= an[r];
#if HAVE_MFMA16
    // P is already the K=16 A-operand: lane l15 = q, k-local = 4g+r
    bf16x4 pa[4];
#pragma unroll
    for (int kc = 0; kc < 4; ++kc) {
      pa[kc][0] = (short)f2bf(p[kc][0]); pa[kc][1] = (short)f2bf(p[kc][1]);
      pa[kc][2] = (short)f2bf(p[kc][2]); pa[kc][3] = (short)f2bf(p[kc][3]);
    }
#pragma unroll
    for (int hf = 0; hf < 4; ++hf) {
      const unsigned short* vrow = Vb + (size_t)(hf * 16 + l15) * 2048 + k0 + 4 * g;
#pragma unroll
      for (int kc = 0; kc < 4; ++kc) {
        bf16x4 bv = *(const bf16x4*)(vrow + kc * 16);
        o[hf] = MFMA16(pa[kc], bv, o[hf]);
      }
    }
#else
    // fallback: LDS transpose P -> K=32 A-frags
    unsigned short (*pw)[72] = plds[wid];
#pragma unroll
    for (int kc = 0; kc < 4; ++kc)
#pragma unroll
      for (int r = 0; r < 4; ++r)
        pw[l15][kc * 16 + 4 * g + r] = f2bf(p[kc][r]);
    asm volatile("s_waitcnt lgkmcnt(0)" ::: "memory");
    __builtin_amdgcn_sched_barrier(0);
    bf16x8 pa0 = *(const bf16x8*)&pw[l15][g * 8];
    bf16x8 pa1 = *(const bf16x8*)&pw[l15][32 + g * 8];
#pragma unroll
    for (int hf = 0; hf < 4; ++hf) {
      const unsigned short* vp = Vb + (size_t)(hf * 16 + l15) * 2048 + k0 + g * 8;
      bf16x8 bv0 = *(const bf16x8*)vp;
      bf16x8 bv1 = *(const bf16x8*)(vp + 32);
      o[hf] = __builtin_amdgcn_mfma_f32_16x16x32_bf16(pa0, bv0, o[hf], 0, 0, 0);
      o[hf] = __builtin_amdgcn_mfma_f32_16x16x32_bf16(pa1, bv1, o[hf], 0, 0, 0);
    }
#endif
  }

  if (SPLIT && q0 + 16 > 512) {
    // partial: unnormalized o + (m, l)
    const int slot = (b * 96 + (qt - 32)) * 4 + s;
    float* pob = po + (size_t)slot * 1024;
#pragma unroll
    for (int hf = 0; hf < 4; ++hf)
#pragma unroll
      for (int r = 0; r < 4; ++r)
        pob[(4 * g + r) * 64 + hf * 16 + l15] = o[hf][r];
    if (lane < 16) {
      pml[slot * 32 + l15] = m;
      pml[slot * 32 + 16 + l15] = lsum;
    }
  } else {
    const float il = 1.f / lsum;
    float iln[4];
#pragma unroll
    for (int r = 0; r < 4; ++r) iln[r] = __shfl(il, 4 * g + r);
    float* ob = out + ((size_t)b * Tn + q0) * 64;
#pragma unroll
    for (int hf = 0; hf < 4; ++hf)
#pragma unroll
      for (int r = 0; r < 4; ++r)
        ob[(size_t)(4 * g + r) * 64 + hf * 16 + l15] = o[hf][r] * iln[r];
  }
}

// ---------------------------------------------------------------------------
// k_comb: merge 2..4 partial segments per (b, qt>=32). grid=(96,8), block=64.
// ---------------------------------------------------------------------------
__global__ __launch_bounds__(64) void k_comb(const float* __restrict__ po,
                                             const float* __restrict__ pml,
                                             float* __restrict__ out) {
  const int qt = 32 + blockIdx.x;
  const int b = blockIdx.y;
  const int nseg = 1 + (qt >> 5);
  const int r = threadIdx.x >> 2;
  const int cg = threadIdx.x & 3;
  const int slot0 = (b * 96 + (qt - 32)) * 4;

  float mv[4], lv[4], M = -1e30f;
#pragma unroll
  for (int s = 0; s < 4; ++s)
    if (s < nseg) {
      mv[s] = pml[(slot0 + s) * 32 + r];
      lv[s] = pml[(slot0 + s) * 32 + 16 + r];
      M = fmaxf(M, mv[s]);
    }
  float w[4], L = 0.f;
#pragma unroll
  for (int s = 0; s < 4; ++s)
    if (s < nseg) { w[s] = exp2f(mv[s] - M); L += w[s] * lv[s]; }

  float acc[16];
#pragma unroll
  for (int c = 0; c < 16; ++c) acc[c] = 0.f;
#pragma unroll
  for (int s = 0; s < 4; ++s)
    if (s < nseg) {
      const float* pb = po + (size_t)(slot0 + s) * 1024 + r * 64 + cg * 16;
#pragma unroll
      for (int j = 0; j < 4; ++j) {
        float4 v = *(const float4*)(pb + 4 * j);
        acc[4 * j + 0] += w[s] * v.x; acc[4 * j + 1] += w[s] * v.y;
        acc[4 * j + 2] += w[s] * v.z; acc[4 * j + 3] += w[s] * v.w;
      }
    }
  const float invL = 1.f / L;
  float* ob = out + ((size_t)(b * Tn + qt * 16 + r)) * 64 + cg * 16;
#pragma unroll
  for (int j = 0; j < 4; ++j) {
    float4 v;
    v.x = acc[4 * j + 0] * invL; v.y = acc[4 * j + 1] * invL;
    v.z = acc[4 * j + 2] * invL; v.w = acc[4 * j + 3] * invL;
    *(float4*)(ob + 4 * j) = v;
  }
}

// ---------------------------------------------------------------------------
extern "C" void kernel_launch(void* const* d_in, const int* in_sizes, int n_in,
                              void* d_out, int out_size, void* d_ws, size_t ws_size,
                              hipStream_t stream) {
  const float* x  = (const float*)d_in[0];
  const float* Wq = (const float*)d_in[1];
  const float* Wk = (const float*)d_in[2];
  const float* Wv = (const float*)d_in[3];
  float* out = (float*)d_out;

  // ws layout (bf16): Wt[3*64*1024] | Q | K | Vt  (each B*T*64)
  unsigned short* Wt = (unsigned short*)d_ws;
  unsigned short* Qs = Wt + 3 * 64 * 1024;
  unsigned short* Ks = Qs + (size_t)Bn * Tn * Hn;
  unsigned short* Vt = Ks + (size_t)Bn * Tn * Hn;
  const size_t bf_bytes = (3 * 64 * 1024 + 3 * (size_t)Bn * Tn * Hn) * 2;
  // fp32 partials: po[3072][1024] + pml[3072][32]
  float* po = (float*)((char*)d_ws + bf_bytes);
  float* pml = po + (size_t)3072 * 1024;
  const size_t need = bf_bytes + ((size_t)3072 * 1024 + 3072 * 32) * 4;

  hipLaunchKernelGGL(k_prep, dim3(192), dim3(256), 0, stream, Wq, Wk, Wv, Wt);
  hipLaunchKernelGGL(k_qkv, dim3(512), dim3(256), 0, stream, x, Wt, Qs, Ks, Vt);
  if (ws_size >= need) {
    hipLaunchKernelGGL((k_attn<true>), dim3(640), dim3(256), 0, stream, Qs, Ks, Vt, out, po, pml);
    hipLaunchKernelGGL(k_comb, dim3(96, 8), dim3(64), 0, stream, po, pml, out);
  } else {
    hipLaunchKernelGGL((k_attn<false>), dim3(256), dim3(256), 0, stream, Qs, Ks, Vt, out, po, pml);
  }
}